// Round 5
// baseline (546.230 us; speedup 1.0000x reference)
//
#include <hip/hip_runtime.h>
#include <hip/hip_bf16.h>

typedef unsigned short u16;
typedef __attribute__((ext_vector_type(8))) short short8;
typedef __attribute__((ext_vector_type(4))) float f32x4;

#define T_LEN 4096
#define NH 6
#define MODEL 768
#define SCALE_QK 0.08838834764831845f
#define NEG_BIG 1e30f

__device__ __forceinline__ float bf2f_r5(u16 u) {
  unsigned int x = ((unsigned int)u) << 16;
  return __uint_as_float(x);
}
__device__ __forceinline__ u16 f2bf_r5(float f) {
  unsigned int x = __float_as_uint(f);
  unsigned int r = (x + 0x7FFFu + ((x >> 16) & 1u)) >> 16;
  return (u16)r;
}

__device__ __forceinline__ void lds_ld16_r5(const u16* g, u16* l) {
  __builtin_amdgcn_global_load_lds((const __attribute__((address_space(1))) void*)g,
                                   (__attribute__((address_space(3))) void*)l, 16, 0, 0);
}

// ---------------------------------------------------------------------------
// r5 Kernel 1: convert x f32 -> bf16 into workspace.  786432 float4 units.
// ---------------------------------------------------------------------------
__global__ __launch_bounds__(256) void r5_cvt_x(const float* __restrict__ x,
                                                u16* __restrict__ xb) {
  int i = blockIdx.x * 256 + threadIdx.x;
  float4 v = ((const float4*)x)[i];
  ushort4 o;
  o.x = f2bf_r5(v.x); o.y = f2bf_r5(v.y); o.z = f2bf_r5(v.z); o.w = f2bf_r5(v.w);
  ((ushort4*)xb)[i] = o;
}

// ---------------------------------------------------------------------------
// r5 Kernel 2: GEMM  C[4096][768] = A_bf16[4096][768] * W_f32[768][768]^T
// W converted f32->bf16 on the fly during LDS staging.  128x128 tile, BK=32,
// 4 waves, 4x4 16x16x32 bf16 MFMA fragments.  Output bf16 (to ws) or f32
// (final projection straight to d_out) via template.
// ---------------------------------------------------------------------------
template <bool F32OUT>
__global__ __launch_bounds__(256) void r5_gemm(const u16* __restrict__ A,
                                               const float* __restrict__ W,
                                               void* __restrict__ Cv) {
  __shared__ u16 As[128 * 32];
  __shared__ u16 Bs[128 * 32];
  const int tid = threadIdx.x;
  const int w = tid >> 6, l = tid & 63;
  const int lr = l & 15, lg = l >> 4;
  const int m0 = blockIdx.x * 128, n0 = blockIdx.y * 128;
  const int wr = (w >> 1) * 64, wc = (w & 1) * 64;
  const int sr = w * 32 + (l >> 2);   // A staging row (issue 0); issue 1 = +16
  const int sc = (l & 3) * 8;         // A staging col (elements)
  const int qrow = tid >> 1;          // W staging row 0..127
  const int qoff = (tid & 1) * 16;    // W staging k-offset in floats
  f32x4 acc[4][4] = {};
  for (int k0 = 0; k0 < 768; k0 += 32) {
    __syncthreads();
    lds_ld16_r5(A + (size_t)(m0 + sr) * 768 + k0 + sc, As + (w * 2 + 0) * 512);
    lds_ld16_r5(A + (size_t)(m0 + sr + 16) * 768 + k0 + sc, As + (w * 2 + 1) * 512);
    {
      const float* wp = W + (size_t)(n0 + qrow) * 768 + k0 + qoff;
      u16* bp = Bs + qrow * 32 + qoff;
#pragma unroll
      for (int q = 0; q < 4; q++) {
        float4 f = ((const float4*)wp)[q];
        ushort4 b;
        b.x = f2bf_r5(f.x); b.y = f2bf_r5(f.y); b.z = f2bf_r5(f.z); b.w = f2bf_r5(f.w);
        *(ushort4*)(bp + q * 4) = b;
      }
    }
    __syncthreads();
    short8 af[4], bfr[4];
#pragma unroll
    for (int mr = 0; mr < 4; mr++) af[mr] = *(const short8*)(As + (wr + mr * 16 + lr) * 32 + lg * 8);
#pragma unroll
    for (int nc = 0; nc < 4; nc++) bfr[nc] = *(const short8*)(Bs + (wc + nc * 16 + lr) * 32 + lg * 8);
#pragma unroll
    for (int mr = 0; mr < 4; mr++)
#pragma unroll
      for (int nc = 0; nc < 4; nc++)
        acc[mr][nc] = __builtin_amdgcn_mfma_f32_16x16x32_bf16(af[mr], bfr[nc], acc[mr][nc], 0, 0, 0);
  }
#pragma unroll
  for (int mr = 0; mr < 4; mr++)
#pragma unroll
    for (int nc = 0; nc < 4; nc++)
#pragma unroll
      for (int ri = 0; ri < 4; ri++) {
        int row = m0 + wr + mr * 16 + lg * 4 + ri;
        int col = n0 + wc + nc * 16 + lr;
        if (F32OUT) {
          ((float*)Cv)[(size_t)row * 768 + col] = acc[mr][nc][ri];
        } else {
          ((u16*)Cv)[(size_t)row * 768 + col] = f2bf_r5(acc[mr][nc][ri]);
        }
      }
}

// ---------------------------------------------------------------------------
// r5 Kernel 3: fused RMS-norm + rotary for Q,K and lambda-mix for V.
// One wave per (t, head) row; lane handles dims (l, l+64) = rotary pair.
// ---------------------------------------------------------------------------
__global__ __launch_bounds__(256) void r5_normrope(u16* __restrict__ qb,
                                                   u16* __restrict__ kb,
                                                   u16* __restrict__ vb,
                                                   const float* __restrict__ vres,
                                                   const float* __restrict__ lambp,
                                                   const int* __restrict__ pos) {
  const int wg = blockIdx.x * 4 + (threadIdx.x >> 6);
  const int l = threadIdx.x & 63;
  const int t = wg / 6;
  const int h = wg - t * 6;
  const size_t base = (size_t)t * MODEL + h * 128;
  const float EPS = 1.1920928955078125e-07f;

  float c = 1.0f, sn = 0.0f;
  if (l < 32) {
    float af = exp2f(-10.0f * (float)l * (1.0f / 31.0f));
    float th = (float)pos[t] * af;
    sincosf(th, &sn, &c);
  }
  {
    float a = bf2f_r5(qb[base + l]), b = bf2f_r5(qb[base + 64 + l]);
    float ss = a * a + b * b;
#pragma unroll
    for (int off = 32; off; off >>= 1) ss += __shfl_xor(ss, off);
    float r = rsqrtf(ss * (1.0f / 128.0f) + EPS);
    float an = a * r, bn = b * r;
    qb[base + l] = f2bf_r5(an * c + bn * sn);
    qb[base + 64 + l] = f2bf_r5(bn * c - an * sn);
  }
  {
    float a = bf2f_r5(kb[base + l]), b = bf2f_r5(kb[base + 64 + l]);
    float ss = a * a + b * b;
#pragma unroll
    for (int off = 32; off; off >>= 1) ss += __shfl_xor(ss, off);
    float r = rsqrtf(ss * (1.0f / 128.0f) + EPS);
    float an = a * r, bn = b * r;
    kb[base + l] = f2bf_r5(an * c + bn * sn);
    kb[base + 64 + l] = f2bf_r5(bn * c - an * sn);
  }
  {
    float lm = *lambp;
    float a = bf2f_r5(vb[base + l]), b = bf2f_r5(vb[base + 64 + l]);
    float ra = vres[base + l], rb = vres[base + 64 + l];
    vb[base + l] = f2bf_r5((1.0f - lm) * a + lm * ra);
    vb[base + 64 + l] = f2bf_r5((1.0f - lm) * b + lm * rb);
  }
}

// ---------------------------------------------------------------------------
// r5 Kernel 4: causal flash attention.  grid (64, 6), 4 waves.
// Wave w owns 16 q-rows.  KV tile 64.  Q frags in regs, K frags from L2,
// P in per-wave LDS, V^T staged in shared LDS.  Output bf16 to ws.
// ---------------------------------------------------------------------------
__global__ __launch_bounds__(256) void r5_attn(const u16* __restrict__ Q,
                                               const u16* __restrict__ K,
                                               const u16* __restrict__ V,
                                               u16* __restrict__ Y) {
  const int h = blockIdx.y;
  const int q0 = blockIdx.x * 64;
  const int tid = threadIdx.x;
  const int w = tid >> 6, l = tid & 63;
  const int lr = l & 15, lg = l >> 4;

  __shared__ u16 vt[128][72];
  __shared__ u16 pls[4][16][72];

  const int qr = q0 + w * 16;
  short8 qf[4];
  {
    const u16* qp = Q + (size_t)(qr + lr) * MODEL + h * 128 + lg * 8;
#pragma unroll
    for (int kc = 0; kc < 4; kc++) qf[kc] = *(const short8*)(qp + kc * 32);
  }
  f32x4 oacc[8] = {};
  float m_i[4], l_i[4];
#pragma unroll
  for (int ri = 0; ri < 4; ri++) { m_i[ri] = -NEG_BIG; l_i[ri] = 0.0f; }

  const int nkv = blockIdx.x + 1;
  for (int kv = 0; kv < nkv; kv++) {
    const int k0 = kv * 64;
    __syncthreads();
    {
      int r = tid >> 5;
      int cc = (tid & 31) * 4;
#pragma unroll
      for (int it = 0; it < 8; it++, r += 8) {
        const u16* vp = V + (size_t)(k0 + r) * MODEL + h * 128 + cc;
        ushort4 vv = *(const ushort4*)vp;
        vt[cc][r] = vv.x;
        vt[cc + 1][r] = vv.y;
        vt[cc + 2][r] = vv.z;
        vt[cc + 3][r] = vv.w;
      }
    }
    f32x4 sac[4] = {};
#pragma unroll
    for (int ct = 0; ct < 4; ct++) {
      const u16* kp = K + (size_t)(k0 + ct * 16 + lr) * MODEL + h * 128 + lg * 8;
#pragma unroll
      for (int kc = 0; kc < 4; kc++) {
        short8 kf = *(const short8*)(kp + kc * 32);
        sac[ct] = __builtin_amdgcn_mfma_f32_16x16x32_bf16(qf[kc], kf, sac[ct], 0, 0, 0);
      }
    }
    float fac[4];
#pragma unroll
    for (int ri = 0; ri < 4; ri++) {
      const int row = qr + lg * 4 + ri;
      float sv[4];
      float mx = -NEG_BIG;
#pragma unroll
      for (int ct = 0; ct < 4; ct++) {
        int col = k0 + ct * 16 + lr;
        float xs = sac[ct][ri] * SCALE_QK;
        sv[ct] = (col <= row) ? xs : -NEG_BIG;
        mx = fmaxf(mx, sv[ct]);
      }
#pragma unroll
      for (int off = 8; off; off >>= 1) mx = fmaxf(mx, __shfl_xor(mx, off));
      float mn = fmaxf(m_i[ri], mx);
      float f = __expf(m_i[ri] - mn);
      float rs = 0.0f;
#pragma unroll
      for (int ct = 0; ct < 4; ct++) {
        float p = __expf(sv[ct] - mn);
        rs += p;
        pls[w][lg * 4 + ri][ct * 16 + lr] = f2bf_r5(p);
      }
#pragma unroll
      for (int off = 8; off; off >>= 1) rs += __shfl_xor(rs, off);
      l_i[ri] = l_i[ri] * f + rs;
      m_i[ri] = mn;
      fac[ri] = f;
    }
#pragma unroll
    for (int dt = 0; dt < 8; dt++)
#pragma unroll
      for (int ri = 0; ri < 4; ri++) oacc[dt][ri] *= fac[ri];
    __syncthreads();
#pragma unroll
    for (int kc2 = 0; kc2 < 2; kc2++) {
      short8 pf = *(const short8*)(&pls[w][lr][kc2 * 32 + lg * 8]);
#pragma unroll
      for (int dt = 0; dt < 8; dt++) {
        short8 vf = *(const short8*)(&vt[dt * 16 + lr][kc2 * 32 + lg * 8]);
        oacc[dt] = __builtin_amdgcn_mfma_f32_16x16x32_bf16(pf, vf, oacc[dt], 0, 0, 0);
      }
    }
  }
#pragma unroll
  for (int dt = 0; dt < 8; dt++)
#pragma unroll
    for (int ri = 0; ri < 4; ri++) {
      int row = qr + lg * 4 + ri;
      Y[(size_t)row * MODEL + h * 128 + dt * 16 + lr] = f2bf_r5(oacc[dt][ri] / l_i[ri]);
    }
}

// ---------------------------------------------------------------------------
// d_out is FLOAT32 (reference output dtype): out0 = y@Wo^T [3145728 f32],
// out1 = v_residual verbatim [3145728 f32].
// Workspace (u16 elems), 25.2 MB:
//   xb @ 0        (3145728)  -- bf16 x; dead after QKV GEMMs; Y aliases it
//   qb @ 3145728  kb @ 6291456  vb @ 9437184
// ---------------------------------------------------------------------------
extern "C" void kernel_launch(void* const* d_in, const int* in_sizes, int n_in,
                              void* d_out, int out_size, void* d_ws, size_t ws_size,
                              hipStream_t stream) {
  const float* x = (const float*)d_in[0];
  const float* vres = (const float*)d_in[1];
  const float* Wq = (const float*)d_in[2];
  const float* Wk = (const float*)d_in[3];
  const float* Wv = (const float*)d_in[4];
  const float* Wo = (const float*)d_in[5];
  const float* lamb = (const float*)d_in[6];
  const int* pos = (const int*)d_in[7];
  float* out = (float*)d_out;

  u16* xb = (u16*)d_ws;
  u16* qb = xb + 3145728;
  u16* kb = qb + 3145728;
  u16* vb = kb + 3145728;
  u16* yb = xb;                   // alias: xb dead after the three QKV GEMMs
  float* out1 = out + 3145728;    // FLOAT offset — output 1 region

  // output 1: exact f32 copy of v_residual
  hipMemcpyAsync(out1, vres, 3145728 * sizeof(float), hipMemcpyDeviceToDevice, stream);

  r5_cvt_x<<<3072, 256, 0, stream>>>(x, xb);
  r5_gemm<false><<<dim3(32, 6), 256, 0, stream>>>(xb, Wq, qb);
  r5_gemm<false><<<dim3(32, 6), 256, 0, stream>>>(xb, Wk, kb);
  r5_gemm<false><<<dim3(32, 6), 256, 0, stream>>>(xb, Wv, vb);
  r5_normrope<<<6144, 256, 0, stream>>>(qb, kb, vb, vres, lamb, pos);
  r5_attn<<<dim3(64, 6), 256, 0, stream>>>(qb, kb, vb, yb);
  r5_gemm<true><<<dim3(32, 6), 256, 0, stream>>>(yb, Wo, (void*)out);
}

// Round 6
// 255.107 us; speedup vs baseline: 2.1412x; 2.1412x over previous
//
#include <hip/hip_runtime.h>
#include <hip/hip_bf16.h>

typedef unsigned short u16;
typedef __attribute__((ext_vector_type(8))) short short8;
typedef __attribute__((ext_vector_type(4))) float f32x4;

#define MODEL 768
#define SCALE_QK 0.08838834764831845f
#define NEG_BIG 1e30f

__device__ __forceinline__ float bf2f(u16 u) {
  unsigned int x = ((unsigned int)u) << 16;
  return __uint_as_float(x);
}
__device__ __forceinline__ u16 f2bf(float f) {
  unsigned int x = __float_as_uint(f);
  unsigned int r = (x + 0x7FFFu + ((x >> 16) & 1u)) >> 16;
  return (u16)r;
}
__device__ __forceinline__ void lds_ld16(const u16* g, u16* l) {
  __builtin_amdgcn_global_load_lds((const __attribute__((address_space(1))) void*)g,
                                   (__attribute__((address_space(3))) void*)l, 16, 0, 0);
}

// ---------------------------------------------------------------------------
// Kernel 1: x f32 -> bf16 (786432 float4 units)
// ---------------------------------------------------------------------------
__global__ __launch_bounds__(256) void r6_cvt_x(const float* __restrict__ x,
                                                u16* __restrict__ xb) {
  int i = blockIdx.x * 256 + threadIdx.x;
  float4 v = ((const float4*)x)[i];
  ushort4 o;
  o.x = f2bf(v.x); o.y = f2bf(v.y); o.z = f2bf(v.z); o.w = f2bf(v.w);
  ((ushort4*)xb)[i] = o;
}

// ---------------------------------------------------------------------------
// GEMM body: C[4096][768] = A_bf16 * W_f32^T, 128x128 tile, BK=32, 4 waves,
// 4x4 16x16x32 bf16 MFMA.  W converted f32->bf16 during staging.
// ---------------------------------------------------------------------------
template <int F32OUT>
__device__ __forceinline__ void gemm_body(const u16* __restrict__ A,
                                          const float* __restrict__ W,
                                          void* __restrict__ Cv) {
  __shared__ u16 As[128 * 32];
  __shared__ u16 Bs[128 * 32];
  const int tid = threadIdx.x;
  const int w = tid >> 6, l = tid & 63;
  const int lr = l & 15, lg = l >> 4;
  const int m0 = blockIdx.x * 128, n0 = blockIdx.y * 128;
  const int wr = (w >> 1) * 64, wc = (w & 1) * 64;
  const int sr = w * 32 + (l >> 2);
  const int sc = (l & 3) * 8;
  const int qrow = tid >> 1;
  const int qoff = (tid & 1) * 16;
  f32x4 acc[4][4] = {};
  for (int k0 = 0; k0 < 768; k0 += 32) {
    __syncthreads();
    lds_ld16(A + (size_t)(m0 + sr) * 768 + k0 + sc, As + (w * 2 + 0) * 512);
    lds_ld16(A + (size_t)(m0 + sr + 16) * 768 + k0 + sc, As + (w * 2 + 1) * 512);
    {
      const float* wp = W + (size_t)(n0 + qrow) * 768 + k0 + qoff;
      u16* bp = Bs + qrow * 32 + qoff;
#pragma unroll
      for (int q = 0; q < 4; q++) {
        float4 f = ((const float4*)wp)[q];
        ushort4 b;
        b.x = f2bf(f.x); b.y = f2bf(f.y); b.z = f2bf(f.z); b.w = f2bf(f.w);
        *(ushort4*)(bp + q * 4) = b;
      }
    }
    __syncthreads();
    short8 af[4], bfr[4];
#pragma unroll
    for (int mr = 0; mr < 4; mr++) af[mr] = *(const short8*)(As + (wr + mr * 16 + lr) * 32 + lg * 8);
#pragma unroll
    for (int nc = 0; nc < 4; nc++) bfr[nc] = *(const short8*)(Bs + (wc + nc * 16 + lr) * 32 + lg * 8);
#pragma unroll
    for (int mr = 0; mr < 4; mr++)
#pragma unroll
      for (int nc = 0; nc < 4; nc++)
        acc[mr][nc] = __builtin_amdgcn_mfma_f32_16x16x32_bf16(af[mr], bfr[nc], acc[mr][nc], 0, 0, 0);
  }
#pragma unroll
  for (int mr = 0; mr < 4; mr++)
#pragma unroll
    for (int nc = 0; nc < 4; nc++)
#pragma unroll
      for (int ri = 0; ri < 4; ri++) {
        int row = m0 + wr + mr * 16 + lg * 4 + ri;
        int col = n0 + wc + nc * 16 + lr;
        if (F32OUT) ((float*)Cv)[(size_t)row * 768 + col] = acc[mr][nc][ri];
        else        ((u16*)Cv)[(size_t)row * 768 + col] = f2bf(acc[mr][nc][ri]);
      }
}

// Q,K,V projections in one dispatch: grid (32, 6, 3)
__global__ __launch_bounds__(256) void r6_gemm_qkv(const u16* __restrict__ A,
                                                   const float* __restrict__ W0,
                                                   const float* __restrict__ W1,
                                                   const float* __restrict__ W2,
                                                   u16* __restrict__ C0,
                                                   u16* __restrict__ C1,
                                                   u16* __restrict__ C2) {
  const float* W = (blockIdx.z == 0) ? W0 : (blockIdx.z == 1) ? W1 : W2;
  u16* C = (blockIdx.z == 0) ? C0 : (blockIdx.z == 1) ? C1 : C2;
  gemm_body<0>(A, W, (void*)C);
}

// Final projection -> f32 straight to d_out
__global__ __launch_bounds__(256) void r6_gemm_proj(const u16* __restrict__ A,
                                                    const float* __restrict__ W,
                                                    float* __restrict__ C) {
  gemm_body<1>(A, W, (void*)C);
}

// ---------------------------------------------------------------------------
// Kernel 3: fused RMS-norm + rotary (Q,K) + lambda-mix (V), in place.
// ---------------------------------------------------------------------------
__global__ __launch_bounds__(256) void r6_normrope(u16* __restrict__ qb,
                                                   u16* __restrict__ kb,
                                                   u16* __restrict__ vb,
                                                   const float* __restrict__ vres,
                                                   const float* __restrict__ lambp,
                                                   const int* __restrict__ pos) {
  const int wg = blockIdx.x * 4 + (threadIdx.x >> 6);
  const int l = threadIdx.x & 63;
  const int t = wg / 6;
  const int h = wg - t * 6;
  const size_t base = (size_t)t * MODEL + h * 128;
  const float EPS = 1.1920928955078125e-07f;

  float c = 1.0f, sn = 0.0f;
  if (l < 32) {
    float af = exp2f(-10.0f * (float)l * (1.0f / 31.0f));
    float th = (float)pos[t] * af;
    sincosf(th, &sn, &c);
  }
  {
    float a = bf2f(qb[base + l]), b = bf2f(qb[base + 64 + l]);
    float ss = a * a + b * b;
#pragma unroll
    for (int off = 32; off; off >>= 1) ss += __shfl_xor(ss, off);
    float r = rsqrtf(ss * (1.0f / 128.0f) + EPS);
    float an = a * r, bn = b * r;
    qb[base + l] = f2bf(an * c + bn * sn);
    qb[base + 64 + l] = f2bf(bn * c - an * sn);
  }
  {
    float a = bf2f(kb[base + l]), b = bf2f(kb[base + 64 + l]);
    float ss = a * a + b * b;
#pragma unroll
    for (int off = 32; off; off >>= 1) ss += __shfl_xor(ss, off);
    float r = rsqrtf(ss * (1.0f / 128.0f) + EPS);
    float an = a * r, bn = b * r;
    kb[base + l] = f2bf(an * c + bn * sn);
    kb[base + 64 + l] = f2bf(bn * c - an * sn);
  }
  {
    float lm = *lambp;
    float a = bf2f(vb[base + l]), b = bf2f(vb[base + 64 + l]);
    float ra = vres[base + l], rb = vres[base + 64 + l];
    vb[base + l] = f2bf((1.0f - lm) * a + lm * ra);
    vb[base + 64 + l] = f2bf((1.0f - lm) * b + lm * rb);
  }
}

// ---------------------------------------------------------------------------
// Kernel 4: causal flash attention, balanced pairing.
// grid (32, 6), 256 threads (4 waves, each owns 16 q-rows).
// wg j processes q-tiles {j, 63-j} (64 rows each) -> 65 KV-iters per wg.
// K: LDS double-buffered via global_load_lds, source-XOR-swizzled.
// V^T: LDS double-buffered, ushort2 swizzled transpose writes.
// ---------------------------------------------------------------------------
__global__ __launch_bounds__(256) void r6_attn(const u16* __restrict__ Q,
                                               const u16* __restrict__ K,
                                               const u16* __restrict__ V,
                                               u16* __restrict__ Y) {
  const int h = blockIdx.y;
  const int j = blockIdx.x;
  const int tid = threadIdx.x;
  const int w = tid >> 6, l = tid & 63;
  const int lr = l & 15, lg = l >> 4;

  __shared__ u16 Ks[2][64][128];   // 32 KB, swizzled blocks: blk^(row&7)
  __shared__ u16 vt[2][128][72];   // 36 KB, V^T, r-index swizzled r^((d>>2&7)<<3)
  __shared__ u16 pls[4][16][72];   // 9 KB, per-wave P

  const int c_ = tid & 31;         // V-stage d-group (4 dims)
  const int cc = c_ * 4;
  const int rp0 = tid >> 5;        // 0..7: V-stage row-pair base
  const int vswz = (c_ & 7) << 3;

  for (int ph = 0; ph < 2; ph++) {
    const int qtile = ph ? (63 - j) : j;
    const int ntiles = qtile + 1;
    const int qr = qtile * 64 + w * 16;

    short8 qf[4];
    {
      const u16* qp = Q + (size_t)(qr + lr) * MODEL + h * 128 + lg * 8;
#pragma unroll
      for (int kc = 0; kc < 4; kc++) qf[kc] = *(const short8*)(qp + kc * 32);
    }
    f32x4 oacc[8] = {};
    float m_i[4], l_i[4];
#pragma unroll
    for (int ri = 0; ri < 4; ri++) { m_i[ri] = -NEG_BIG; l_i[ri] = 0.0f; }

    // ---- prologue: stage tile 0 into buffer 0 ----
#pragma unroll
    for (int i = 0; i < 4; i++) {
      int rbase = w * 16 + 4 * i;
      int row = rbase + (l >> 4);
      int blk = (l & 15) ^ (row & 7);
      lds_ld16(K + (size_t)row * MODEL + h * 128 + blk * 8, &Ks[0][rbase][0]);
    }
#pragma unroll
    for (int it = 0; it < 4; it++) {
      int rloc = 2 * (rp0 + 8 * it);
      ushort4 va = *(const ushort4*)(V + (size_t)rloc * MODEL + h * 128 + cc);
      ushort4 vb = *(const ushort4*)(V + (size_t)(rloc + 1) * MODEL + h * 128 + cc);
      int rs = rloc ^ vswz;
      u16 a0[4] = {va.x, va.y, va.z, va.w};
      u16 b0[4] = {vb.x, vb.y, vb.z, vb.w};
#pragma unroll
      for (int q = 0; q < 4; q++) {
        ushort2 t2; t2.x = a0[q]; t2.y = b0[q];
        *(ushort2*)&vt[0][cc + q][rs] = t2;
      }
    }
    __syncthreads();

    for (int kv = 0; kv < ntiles; kv++) {
      const int cur = kv & 1, nxt = cur ^ 1;
      const int k0 = kv * 64;
      const bool pre = (kv + 1 < ntiles);

      // ---- issue next-tile staging early (T14) ----
      ushort4 va[4], vb[4];
      if (pre) {
        const int k0n = k0 + 64;
#pragma unroll
        for (int it = 0; it < 4; it++) {
          int rloc = 2 * (rp0 + 8 * it);
          va[it] = *(const ushort4*)(V + (size_t)(k0n + rloc) * MODEL + h * 128 + cc);
          vb[it] = *(const ushort4*)(V + (size_t)(k0n + rloc + 1) * MODEL + h * 128 + cc);
        }
#pragma unroll
        for (int i = 0; i < 4; i++) {
          int rbase = w * 16 + 4 * i;
          int row = rbase + (l >> 4);
          int blk = (l & 15) ^ (row & 7);
          lds_ld16(K + (size_t)(k0n + row) * MODEL + h * 128 + blk * 8, &Ks[nxt][rbase][0]);
        }
      }

      // ---- S = Q K^T from LDS ----
      f32x4 sac[4] = {};
#pragma unroll
      for (int ct = 0; ct < 4; ct++) {
        const int r = ct * 16 + lr;
#pragma unroll
        for (int kc = 0; kc < 4; kc++) {
          short8 kf = *(const short8*)(&Ks[cur][r][((4 * kc + lg) ^ (r & 7)) * 8]);
          sac[ct] = __builtin_amdgcn_mfma_f32_16x16x32_bf16(qf[kc], kf, sac[ct], 0, 0, 0);
        }
      }

      // ---- online softmax ----
      float fac[4];
      const bool diag = (kv == qtile);
#pragma unroll
      for (int ri = 0; ri < 4; ri++) {
        float sv[4];
        if (diag) {
          const int row = qr + lg * 4 + ri;
#pragma unroll
          for (int ct = 0; ct < 4; ct++) {
            int col = k0 + ct * 16 + lr;
            float xs = sac[ct][ri] * SCALE_QK;
            sv[ct] = (col <= row) ? xs : -NEG_BIG;
          }
        } else {
#pragma unroll
          for (int ct = 0; ct < 4; ct++) sv[ct] = sac[ct][ri] * SCALE_QK;
        }
        float mx = fmaxf(fmaxf(sv[0], sv[1]), fmaxf(sv[2], sv[3]));
#pragma unroll
        for (int off = 8; off; off >>= 1) mx = fmaxf(mx, __shfl_xor(mx, off));
        float mn = fmaxf(m_i[ri], mx);
        float f = __expf(m_i[ri] - mn);
        float rs = 0.0f;
#pragma unroll
        for (int ct = 0; ct < 4; ct++) {
          float p = __expf(sv[ct] - mn);
          rs += p;
          pls[w][lg * 4 + ri][ct * 16 + lr] = f2bf(p);
        }
#pragma unroll
        for (int off = 8; off; off >>= 1) rs += __shfl_xor(rs, off);
        l_i[ri] = l_i[ri] * f + rs;
        m_i[ri] = mn;
        fac[ri] = f;
      }
#pragma unroll
      for (int dt = 0; dt < 8; dt++)
#pragma unroll
        for (int ri = 0; ri < 4; ri++) oacc[dt][ri] *= fac[ri];

      // wave-local P visibility (stores above -> reads below, same wave)
      asm volatile("s_waitcnt lgkmcnt(0)" ::: "memory");

      // ---- write V^T[next] (global latency hidden under QK^T+softmax) ----
      if (pre) {
#pragma unroll
        for (int it = 0; it < 4; it++) {
          int rloc = 2 * (rp0 + 8 * it);
          int rs = rloc ^ vswz;
          u16 a0[4] = {va[it].x, va[it].y, va[it].z, va[it].w};
          u16 b0[4] = {vb[it].x, vb[it].y, vb[it].z, vb[it].w};
#pragma unroll
          for (int q = 0; q < 4; q++) {
            ushort2 t2; t2.x = a0[q]; t2.y = b0[q];
            *(ushort2*)&vt[nxt][cc + q][rs] = t2;
          }
        }
      }

      // ---- O += P V ----
#pragma unroll
      for (int kc2 = 0; kc2 < 2; kc2++) {
        short8 pf = *(const short8*)(&pls[w][lr][kc2 * 32 + lg * 8]);
#pragma unroll
        for (int dt = 0; dt < 8; dt++) {
          const int d = dt * 16 + lr;
          const int kb = (kc2 * 32 + lg * 8) ^ (((d >> 2) & 7) << 3);
          short8 vf = *(const short8*)(&vt[cur][d][kb]);
          oacc[dt] = __builtin_amdgcn_mfma_f32_16x16x32_bf16(pf, vf, oacc[dt], 0, 0, 0);
        }
      }
      __syncthreads();  // everyone done with cur & staging of nxt complete (vmcnt drained)
    }

    // ---- write O for this q-tile ----
#pragma unroll
    for (int dt = 0; dt < 8; dt++)
#pragma unroll
      for (int ri = 0; ri < 4; ri++) {
        int row = qr + lg * 4 + ri;
        Y[(size_t)row * MODEL + h * 128 + dt * 16 + lr] = f2bf(oacc[dt][ri] / l_i[ri]);
      }
    __syncthreads();  // protect buffers before phase-2 prologue
  }
}

// ---------------------------------------------------------------------------
// d_out is FLOAT32: out0 = y@Wo^T [3145728 f32], out1 = v_residual [3145728].
// Workspace (u16 elems), 25.2 MB: xb@0 (aliased by yb), qb, kb, vb.
// ---------------------------------------------------------------------------
extern "C" void kernel_launch(void* const* d_in, const int* in_sizes, int n_in,
                              void* d_out, int out_size, void* d_ws, size_t ws_size,
                              hipStream_t stream) {
  const float* x = (const float*)d_in[0];
  const float* vres = (const float*)d_in[1];
  const float* Wq = (const float*)d_in[2];
  const float* Wk = (const float*)d_in[3];
  const float* Wv = (const float*)d_in[4];
  const float* Wo = (const float*)d_in[5];
  const float* lamb = (const float*)d_in[6];
  const int* pos = (const int*)d_in[7];
  float* out = (float*)d_out;

  u16* xb = (u16*)d_ws;
  u16* qb = xb + 3145728;
  u16* kb = qb + 3145728;
  u16* vb = kb + 3145728;
  u16* yb = xb;                   // alias: xb dead after QKV GEMMs
  float* out1 = out + 3145728;

  hipMemcpyAsync(out1, vres, 3145728 * sizeof(float), hipMemcpyDeviceToDevice, stream);

  r6_cvt_x<<<3072, 256, 0, stream>>>(x, xb);
  r6_gemm_qkv<<<dim3(32, 6, 3), 256, 0, stream>>>(xb, Wq, Wk, Wv, qb, kb, vb);
  r6_normrope<<<6144, 256, 0, stream>>>(qb, kb, vb, vres, lamb, pos);
  r6_attn<<<dim3(32, 6), 256, 0, stream>>>(qb, kb, vb, yb);
  r6_gemm_proj<<<dim3(32, 6), 256, 0, stream>>>(yb, Wo, out);
}

// Round 7
// 243.858 us; speedup vs baseline: 2.2399x; 1.0461x over previous
//
#include <hip/hip_runtime.h>
#include <hip/hip_bf16.h>

typedef unsigned short u16;
typedef __attribute__((ext_vector_type(8))) short short8;
typedef __attribute__((ext_vector_type(4))) float f32x4;

#define MODEL 768
// 1/sqrt(128) * log2(e): exp(s/sqrt(128)) == exp2(s * SCALE2)
#define SCALE2 0.1275174137f
#define NEG_BIG 1e30f

__device__ __forceinline__ float bf2f(u16 u) {
  unsigned int x = ((unsigned int)u) << 16;
  return __uint_as_float(x);
}
__device__ __forceinline__ u16 f2bf(float f) {
  unsigned int x = __float_as_uint(f);
  unsigned int r = (x + 0x7FFFu + ((x >> 16) & 1u)) >> 16;
  return (u16)r;
}
__device__ __forceinline__ void lds_ld16(const u16* g, u16* l) {
  __builtin_amdgcn_global_load_lds((const __attribute__((address_space(1))) void*)g,
                                   (__attribute__((address_space(3))) void*)l, 16, 0, 0);
}

// ---------------------------------------------------------------------------
// Kernel 1: x f32 -> bf16 (786432 float4 units)
// ---------------------------------------------------------------------------
__global__ __launch_bounds__(256) void r7_cvt_x(const float* __restrict__ x,
                                                u16* __restrict__ xb) {
  int i = blockIdx.x * 256 + threadIdx.x;
  float4 v = ((const float4*)x)[i];
  ushort4 o;
  o.x = f2bf(v.x); o.y = f2bf(v.y); o.z = f2bf(v.z); o.w = f2bf(v.w);
  ((ushort4*)xb)[i] = o;
}

// ---------------------------------------------------------------------------
// GEMM body: C[4096][768] = A_bf16 * W_f32^T, 128x128 tile, BK=32, 4 waves,
// 4x4 16x16x32 bf16 MFMA.  W converted f32->bf16 during staging.
// ---------------------------------------------------------------------------
template <int F32OUT>
__device__ __forceinline__ void gemm_body(const u16* __restrict__ A,
                                          const float* __restrict__ W,
                                          void* __restrict__ Cv) {
  __shared__ u16 As[128 * 32];
  __shared__ u16 Bs[128 * 32];
  const int tid = threadIdx.x;
  const int w = tid >> 6, l = tid & 63;
  const int lr = l & 15, lg = l >> 4;
  const int m0 = blockIdx.x * 128, n0 = blockIdx.y * 128;
  const int wr = (w >> 1) * 64, wc = (w & 1) * 64;
  const int sr = w * 32 + (l >> 2);
  const int sc = (l & 3) * 8;
  const int qrow = tid >> 1;
  const int qoff = (tid & 1) * 16;
  f32x4 acc[4][4] = {};
  for (int k0 = 0; k0 < 768; k0 += 32) {
    __syncthreads();
    lds_ld16(A + (size_t)(m0 + sr) * 768 + k0 + sc, As + (w * 2 + 0) * 512);
    lds_ld16(A + (size_t)(m0 + sr + 16) * 768 + k0 + sc, As + (w * 2 + 1) * 512);
    {
      const float* wp = W + (size_t)(n0 + qrow) * 768 + k0 + qoff;
      u16* bp = Bs + qrow * 32 + qoff;
#pragma unroll
      for (int q = 0; q < 4; q++) {
        float4 f = ((const float4*)wp)[q];
        ushort4 b;
        b.x = f2bf(f.x); b.y = f2bf(f.y); b.z = f2bf(f.z); b.w = f2bf(f.w);
        *(ushort4*)(bp + q * 4) = b;
      }
    }
    __syncthreads();
    short8 af[4], bfr[4];
#pragma unroll
    for (int mr = 0; mr < 4; mr++) af[mr] = *(const short8*)(As + (wr + mr * 16 + lr) * 32 + lg * 8);
#pragma unroll
    for (int nc = 0; nc < 4; nc++) bfr[nc] = *(const short8*)(Bs + (wc + nc * 16 + lr) * 32 + lg * 8);
#pragma unroll
    for (int mr = 0; mr < 4; mr++)
#pragma unroll
      for (int nc = 0; nc < 4; nc++)
        acc[mr][nc] = __builtin_amdgcn_mfma_f32_16x16x32_bf16(af[mr], bfr[nc], acc[mr][nc], 0, 0, 0);
  }
#pragma unroll
  for (int mr = 0; mr < 4; mr++)
#pragma unroll
    for (int nc = 0; nc < 4; nc++)
#pragma unroll
      for (int ri = 0; ri < 4; ri++) {
        int row = m0 + wr + mr * 16 + lg * 4 + ri;
        int col = n0 + wc + nc * 16 + lr;
        if (F32OUT) ((float*)Cv)[(size_t)row * 768 + col] = acc[mr][nc][ri];
        else        ((u16*)Cv)[(size_t)row * 768 + col] = f2bf(acc[mr][nc][ri]);
      }
}

__global__ __launch_bounds__(256) void r7_gemm_qkv(const u16* __restrict__ A,
                                                   const float* __restrict__ W0,
                                                   const float* __restrict__ W1,
                                                   const float* __restrict__ W2,
                                                   u16* __restrict__ C0,
                                                   u16* __restrict__ C1,
                                                   u16* __restrict__ C2) {
  const float* W = (blockIdx.z == 0) ? W0 : (blockIdx.z == 1) ? W1 : W2;
  u16* C = (blockIdx.z == 0) ? C0 : (blockIdx.z == 1) ? C1 : C2;
  gemm_body<0>(A, W, (void*)C);
}

__global__ __launch_bounds__(256) void r7_gemm_proj(const u16* __restrict__ A,
                                                    const float* __restrict__ W,
                                                    float* __restrict__ C) {
  gemm_body<1>(A, W, (void*)C);
}

// ---------------------------------------------------------------------------
// Kernel 3: fused RMS-norm + rotary (Q,K) + lambda-mix (V), in place.
// ---------------------------------------------------------------------------
__global__ __launch_bounds__(256) void r7_normrope(u16* __restrict__ qb,
                                                   u16* __restrict__ kb,
                                                   u16* __restrict__ vb,
                                                   const float* __restrict__ vres,
                                                   const float* __restrict__ lambp,
                                                   const int* __restrict__ pos) {
  const int wg = blockIdx.x * 4 + (threadIdx.x >> 6);
  const int l = threadIdx.x & 63;
  const int t = wg / 6;
  const int h = wg - t * 6;
  const size_t base = (size_t)t * MODEL + h * 128;
  const float EPS = 1.1920928955078125e-07f;

  float c = 1.0f, sn = 0.0f;
  if (l < 32) {
    float af = exp2f(-10.0f * (float)l * (1.0f / 31.0f));
    float th = (float)pos[t] * af;
    sincosf(th, &sn, &c);
  }
  {
    float a = bf2f(qb[base + l]), b = bf2f(qb[base + 64 + l]);
    float ss = a * a + b * b;
#pragma unroll
    for (int off = 32; off; off >>= 1) ss += __shfl_xor(ss, off);
    float r = rsqrtf(ss * (1.0f / 128.0f) + EPS);
    float an = a * r, bn = b * r;
    qb[base + l] = f2bf(an * c + bn * sn);
    qb[base + 64 + l] = f2bf(bn * c - an * sn);
  }
  {
    float a = bf2f(kb[base + l]), b = bf2f(kb[base + 64 + l]);
    float ss = a * a + b * b;
#pragma unroll
    for (int off = 32; off; off >>= 1) ss += __shfl_xor(ss, off);
    float r = rsqrtf(ss * (1.0f / 128.0f) + EPS);
    float an = a * r, bn = b * r;
    kb[base + l] = f2bf(an * c + bn * sn);
    kb[base + 64 + l] = f2bf(bn * c - an * sn);
  }
  {
    float lm = *lambp;
    float a = bf2f(vb[base + l]), b = bf2f(vb[base + 64 + l]);
    float ra = vres[base + l], rb = vres[base + 64 + l];
    vb[base + l] = f2bf((1.0f - lm) * a + lm * ra);
    vb[base + 64 + l] = f2bf((1.0f - lm) * b + lm * rb);
  }
}

// ---------------------------------------------------------------------------
// Kernel 4: causal flash attention, STATIC-MAX softmax (no cross-lane ops).
// Q,K are RMS-normalized (||row|| = sqrt(128)) and rotary preserves norms,
// so |s*scale| <= ~11.4: P = exp2(s*SCALE2) is bounded in [1e-5, 1e5] and
// needs no running max.  Row sums accumulate via MFMA against a ones-frag
// (same C-layout as oacc -> same-lane divide at the end).
// grid (64, 6); j = 63-bx so longest blocks dispatch first.  4 waves,
// wave w owns 16 q-rows.  K: gload_lds dbuf (src-swizzled); V^T: reg->LDS
// dbuf (swizzled); one barrier per KV-iter.
// ---------------------------------------------------------------------------
__global__ __launch_bounds__(256) void r7_attn(const u16* __restrict__ Q,
                                               const u16* __restrict__ K,
                                               const u16* __restrict__ V,
                                               u16* __restrict__ Y) {
  const int h = blockIdx.y;
  const int j = 63 - blockIdx.x;     // longest first
  const int ntiles = j + 1;
  const int tid = threadIdx.x;
  const int w = tid >> 6, l = tid & 63;
  const int lr = l & 15, lg = l >> 4;

  __shared__ u16 Ks[2][64][128];   // 32 KB, blk^(row&7) swizzle
  __shared__ u16 vt[2][128][72];   // 36 KB, V^T, r ^ ((d>>2&7)<<3)
  __shared__ u16 pls[4][16][72];   // 9 KB, per-wave P

  const int c_ = tid & 31;
  const int cc = c_ * 4;
  const int rp0 = tid >> 5;
  const int vswz = (c_ & 7) << 3;

  short8 ones;
#pragma unroll
  for (int i = 0; i < 8; i++) ones[i] = (short)0x3F80;  // bf16 1.0

  const int qr = j * 64 + w * 16;
  short8 qf[4];
  {
    const u16* qp = Q + (size_t)(qr + lr) * MODEL + h * 128 + lg * 8;
#pragma unroll
    for (int kc = 0; kc < 4; kc++) qf[kc] = *(const short8*)(qp + kc * 32);
  }
  f32x4 oacc[8] = {};
  f32x4 lacc = {};

  // ---- prologue: stage tile 0 into buffer 0 ----
#pragma unroll
  for (int i = 0; i < 4; i++) {
    int rbase = w * 16 + 4 * i;
    int row = rbase + (l >> 4);
    int blk = (l & 15) ^ (row & 7);
    lds_ld16(K + (size_t)row * MODEL + h * 128 + blk * 8, &Ks[0][rbase][0]);
  }
#pragma unroll
  for (int it = 0; it < 4; it++) {
    int rloc = 2 * (rp0 + 8 * it);
    ushort4 va = *(const ushort4*)(V + (size_t)rloc * MODEL + h * 128 + cc);
    ushort4 vb = *(const ushort4*)(V + (size_t)(rloc + 1) * MODEL + h * 128 + cc);
    int rs = rloc ^ vswz;
    u16 a0[4] = {va.x, va.y, va.z, va.w};
    u16 b0[4] = {vb.x, vb.y, vb.z, vb.w};
#pragma unroll
    for (int q = 0; q < 4; q++) {
      ushort2 t2; t2.x = a0[q]; t2.y = b0[q];
      *(ushort2*)&vt[0][cc + q][rs] = t2;
    }
  }
  __syncthreads();

  for (int kv = 0; kv < ntiles; kv++) {
    const int cur = kv & 1, nxt = cur ^ 1;
    const int k0 = kv * 64;
    const bool pre = (kv + 1 < ntiles);

    // ---- issue next-tile staging early ----
    ushort4 va[4], vb[4];
    if (pre) {
      const int k0n = k0 + 64;
#pragma unroll
      for (int it = 0; it < 4; it++) {
        int rloc = 2 * (rp0 + 8 * it);
        va[it] = *(const ushort4*)(V + (size_t)(k0n + rloc) * MODEL + h * 128 + cc);
        vb[it] = *(const ushort4*)(V + (size_t)(k0n + rloc + 1) * MODEL + h * 128 + cc);
      }
#pragma unroll
      for (int i = 0; i < 4; i++) {
        int rbase = w * 16 + 4 * i;
        int row = rbase + (l >> 4);
        int blk = (l & 15) ^ (row & 7);
        lds_ld16(K + (size_t)(k0n + row) * MODEL + h * 128 + blk * 8, &Ks[nxt][rbase][0]);
      }
    }

    // ---- S = Q K^T from LDS ----
    f32x4 sac[4] = {};
    __builtin_amdgcn_s_setprio(1);
#pragma unroll
    for (int ct = 0; ct < 4; ct++) {
      const int r = ct * 16 + lr;
#pragma unroll
      for (int kc = 0; kc < 4; kc++) {
        short8 kf = *(const short8*)(&Ks[cur][r][((4 * kc + lg) ^ (r & 7)) * 8]);
        sac[ct] = __builtin_amdgcn_mfma_f32_16x16x32_bf16(qf[kc], kf, sac[ct], 0, 0, 0);
      }
    }
    __builtin_amdgcn_s_setprio(0);

    // ---- static-max softmax: P = exp2(s*SCALE2), no reductions ----
    const bool diag = (kv == j);
#pragma unroll
    for (int ri = 0; ri < 4; ri++) {
      const int row = qr + lg * 4 + ri;
#pragma unroll
      for (int ct = 0; ct < 4; ct++) {
        float xs = sac[ct][ri] * SCALE2;
        float p;
        if (diag) {
          int col = k0 + ct * 16 + lr;
          p = (col <= row) ? exp2f(xs) : 0.0f;
        } else {
          p = exp2f(xs);
        }
        pls[w][lg * 4 + ri][ct * 16 + lr] = f2bf(p);
      }
    }

    // wave-local P visibility
    asm volatile("s_waitcnt lgkmcnt(0)" ::: "memory");

    // ---- write V^T[next] (latency hidden under QK^T/exp) ----
    if (pre) {
#pragma unroll
      for (int it = 0; it < 4; it++) {
        int rloc = 2 * (rp0 + 8 * it);
        int rs = rloc ^ vswz;
        u16 a0[4] = {va[it].x, va[it].y, va[it].z, va[it].w};
        u16 b0[4] = {vb[it].x, vb[it].y, vb[it].z, vb[it].w};
#pragma unroll
        for (int q = 0; q < 4; q++) {
          ushort2 t2; t2.x = a0[q]; t2.y = b0[q];
          *(ushort2*)&vt[nxt][cc + q][rs] = t2;
        }
      }
    }

    // ---- O += P V;  l += P 1  (rowsum via ones-MFMA) ----
    __builtin_amdgcn_s_setprio(1);
#pragma unroll
    for (int kc2 = 0; kc2 < 2; kc2++) {
      short8 pf = *(const short8*)(&pls[w][lr][kc2 * 32 + lg * 8]);
      lacc = __builtin_amdgcn_mfma_f32_16x16x32_bf16(pf, ones, lacc, 0, 0, 0);
#pragma unroll
      for (int dt = 0; dt < 8; dt++) {
        const int d = dt * 16 + lr;
        const int kb = (kc2 * 32 + lg * 8) ^ (((d >> 2) & 7) << 3);
        short8 vf = *(const short8*)(&vt[cur][d][kb]);
        oacc[dt] = __builtin_amdgcn_mfma_f32_16x16x32_bf16(pf, vf, oacc[dt], 0, 0, 0);
      }
    }
    __builtin_amdgcn_s_setprio(0);
    __syncthreads();  // cur consumed; nxt staging (vmcnt) drained
  }

  // ---- write O ----
#pragma unroll
  for (int dt = 0; dt < 8; dt++)
#pragma unroll
    for (int ri = 0; ri < 4; ri++) {
      int row = qr + lg * 4 + ri;
      Y[(size_t)row * MODEL + h * 128 + dt * 16 + lr] = f2bf(oacc[dt][ri] / lacc[ri]);
    }
}

// ---------------------------------------------------------------------------
// d_out is FLOAT32: out0 = y@Wo^T [3145728 f32], out1 = v_residual [3145728].
// Workspace (u16 elems), 25.2 MB: xb@0 (aliased by yb), qb, kb, vb.
// ---------------------------------------------------------------------------
extern "C" void kernel_launch(void* const* d_in, const int* in_sizes, int n_in,
                              void* d_out, int out_size, void* d_ws, size_t ws_size,
                              hipStream_t stream) {
  const float* x = (const float*)d_in[0];
  const float* vres = (const float*)d_in[1];
  const float* Wq = (const float*)d_in[2];
  const float* Wk = (const float*)d_in[3];
  const float* Wv = (const float*)d_in[4];
  const float* Wo = (const float*)d_in[5];
  const float* lamb = (const float*)d_in[6];
  const int* pos = (const int*)d_in[7];
  float* out = (float*)d_out;

  u16* xb = (u16*)d_ws;
  u16* qb = xb + 3145728;
  u16* kb = qb + 3145728;
  u16* vb = kb + 3145728;
  u16* yb = xb;                   // alias: xb dead after QKV GEMMs
  float* out1 = out + 3145728;

  hipMemcpyAsync(out1, vres, 3145728 * sizeof(float), hipMemcpyDeviceToDevice, stream);

  r7_cvt_x<<<3072, 256, 0, stream>>>(x, xb);
  r7_gemm_qkv<<<dim3(32, 6, 3), 256, 0, stream>>>(xb, Wq, Wk, Wv, qb, kb, vb);
  r7_normrope<<<6144, 256, 0, stream>>>(qb, kb, vb, vres, lamb, pos);
  r7_attn<<<dim3(64, 6), 256, 0, stream>>>(qb, kb, vb, yb);
  r7_gemm_proj<<<dim3(32, 6), 256, 0, stream>>>(yb, Wo, out);
}